// Round 1
// baseline (464.097 us; speedup 1.0000x reference)
//
#include <hip/hip_runtime.h>
#include <math.h>

// SimpleEdgePredictor on MI355X — factored formulation:
//   feat@W1 = P_a[i] + P_b[j] + smear(d)@W1s + type*w320
// Kernel 1 precomputes node projections P_mol/P_fa/P_fb into d_ws.
// Kernel 2 does per-edge smear-GEMM + LayerNorm + ReLU + 256->8 in f32.

#define HID   128
#define MAXF  16
#define NG    64
#define NET   8
#define NB    256
#define NMOL  64
#define HID2  256

#define PMOL_ROWS (NB*NMOL)                    // 16384
#define PF_ROWS   (NB*MAXF)                    // 4096
#define NROWS     (PMOL_ROWS + 2*PF_ROWS)      // 24576
#define PFA_OFF   ((size_t)PMOL_ROWS*HID2)
#define PFB_OFF   ((size_t)(PMOL_ROWS+PF_ROWS)*HID2)

#define E_FF   (NB*MAXF*MAXF)                  // 65536
#define E_MF   (NB*NMOL*MAXF)                  // 262144
#define GRP_FF (E_FF/32)                       // 2048
#define NGROUP ((E_FF+E_MF)/32)                // 10240

#define WSCR_FLOATS 576                        // per-wave: max(8*64 g, 64*9 scr)
#define EDGE_LDS_BYTES ((NG*HID2 + 4*WSCR_FLOATS)*4)  // 74752

// ---------------- node projections: P[r] = h[r] @ W1_half ----------------
__global__ __launch_bounds__(256) void proj_kernel(
    const float* __restrict__ h_mol, const float* __restrict__ h_frag,
    const float* __restrict__ W1, float* __restrict__ P)
{
    __shared__ float hs[8][HID];               // 4 KiB
    const int tid  = threadIdx.x;
    const int row0 = blockIdx.x * 8;

    const float* src; int wrow0;
    if (row0 < PMOL_ROWS)                 { src = h_mol  + (size_t)row0*HID;                      wrow0 = 0;   }
    else if (row0 < PMOL_ROWS + PF_ROWS)  { src = h_frag + (size_t)(row0-PMOL_ROWS)*HID;          wrow0 = 0;   }
    else                                  { src = h_frag + (size_t)(row0-PMOL_ROWS-PF_ROWS)*HID;  wrow0 = HID; }

    // 8 rows x 128 = 1024 floats, one float4 per thread (contiguous rows)
    ((float4*)&hs[0][0])[tid] = ((const float4*)src)[tid];
    __syncthreads();

    float acc[8] = {0.f,0.f,0.f,0.f,0.f,0.f,0.f,0.f};
    const float* wp = W1 + (size_t)wrow0*HID2 + tid;   // column tid, coalesced
    #pragma unroll 4
    for (int k4 = 0; k4 < HID/4; ++k4) {
        const float w0 = wp[(4*k4+0)*HID2];
        const float w1 = wp[(4*k4+1)*HID2];
        const float w2 = wp[(4*k4+2)*HID2];
        const float w3 = wp[(4*k4+3)*HID2];
        #pragma unroll
        for (int r = 0; r < 8; ++r) {
            const float4 h4 = *(const float4*)&hs[r][4*k4];  // b128 broadcast
            acc[r] = fmaf(h4.x, w0, acc[r]);
            acc[r] = fmaf(h4.y, w1, acc[r]);
            acc[r] = fmaf(h4.z, w2, acc[r]);
            acc[r] = fmaf(h4.w, w3, acc[r]);
        }
    }
    float* dst = P + (size_t)row0*HID2 + tid;
    #pragma unroll
    for (int r = 0; r < 8; ++r) dst[r*HID2] = acc[r];
}

// ---------------- per-edge: smear-GEMM + LN + ReLU + W2 ----------------
__global__ __launch_bounds__(256,2) void edge_kernel(
    const float* __restrict__ pos_mol, const float* __restrict__ pos_frag,
    const float* __restrict__ W1, const float* __restrict__ b1,
    const float* __restrict__ ln_g, const float* __restrict__ ln_b,
    const float* __restrict__ W2, const float* __restrict__ b2,
    const float* __restrict__ P, float* __restrict__ out)
{
    extern __shared__ float smem[];
    const int tid  = threadIdx.x;
    const int lane = tid & 63;
    const int wid  = tid >> 6;
    float* W1s  = smem;                               // [64][256] f32 = 64 KiB
    float* wscr = smem + NG*HID2 + wid*WSCR_FLOATS;   // per-wave scratch

    // stage W1 rows 256..319 (smear weights) into LDS: 16384 floats
    {
        const float4* s4 = (const float4*)(W1 + 256*HID2);
        float4* d4 = (float4*)W1s;
        #pragma unroll
        for (int i = 0; i < 16; ++i) d4[i*256 + tid] = s4[i*256 + tid];
    }

    // per-lane constants (channels c = 4*lane .. 4*lane+3)
    const float4 b14  = ((const float4*)b1)[lane];
    const float4 lg4  = ((const float4*)ln_g)[lane];
    const float4 lb4  = ((const float4*)ln_b)[lane];
    const float4 w320 = ((const float4*)(W1 + 320*HID2))[lane];
    const float  b2l  = b2[lane & 7];
    const float  delta = 10.0f/63.0f;
    const float  off   = delta * (float)lane;
    const float  coeff = -0.5f/(delta*delta);
    __syncthreads();

    for (int grp = blockIdx.x; grp < NGROUP; grp += gridDim.x) {
        const bool is_mf = (grp >= GRP_FF);
        const int  e0 = (is_mf ? (grp - GRP_FF) : grp) * 32 + wid * 8;

        float4 acc[8];
        #pragma unroll
        for (int t = 0; t < 8; ++t) {
            const int e = e0 + t;
            int arow, brow;
            const float* pa;
            if (is_mf) {
                const int bg = e >> 10, m = (e >> 4) & 63, j = e & 15;
                arow = bg*NMOL + m; brow = bg*MAXF + j;
                pa = pos_mol + (size_t)arow*3;
            } else {
                const int bg = e >> 8, i = (e >> 4) & 15, j = e & 15;
                arow = bg*MAXF + i; brow = bg*MAXF + j;
                pa = pos_frag + (size_t)arow*3;
            }
            const float* pb = pos_frag + (size_t)brow*3;
            const float dx = pa[0]-pb[0], dy = pa[1]-pb[1], dz = pa[2]-pb[2];
            const float d  = sqrtf(fmaf(dx,dx, fmaf(dy,dy, fmaf(dz,dz, 1e-12f))));
            const float dd = d - off;
            wscr[t*64 + lane] = expf(coeff*dd*dd);    // g[t][k=lane]

            const float* pra = P + (is_mf ? (size_t)arow*HID2 : PFA_OFF + (size_t)arow*HID2);
            const float* prb = P + PFB_OFF + (size_t)brow*HID2;
            const float4 av = ((const float4*)pra)[lane];
            const float4 bv = ((const float4*)prb)[lane];
            float4 c;
            c.x = av.x + bv.x + b14.x;
            c.y = av.y + bv.y + b14.y;
            c.z = av.z + bv.z + b14.z;
            c.w = av.w + bv.w + b14.w;
            if (is_mf) { c.x += w320.x; c.y += w320.y; c.z += w320.z; c.w += w320.w; }
            acc[t] = c;
        }
        __builtin_amdgcn_wave_barrier();   // wave-synchronous LDS g handoff

        // smear GEMM: acc[t][c] += sum_k g[t][k] * W1s[k][c]
        const float4* w4 = (const float4*)W1s;
        #pragma unroll 2
        for (int k4 = 0; k4 < 16; ++k4) {
            const float4 w0 = w4[(4*k4+0)*64 + lane];
            const float4 w1 = w4[(4*k4+1)*64 + lane];
            const float4 w2 = w4[(4*k4+2)*64 + lane];
            const float4 w3 = w4[(4*k4+3)*64 + lane];
            #pragma unroll
            for (int t = 0; t < 8; ++t) {
                const float4 g = *(const float4*)&wscr[t*64 + 4*k4]; // broadcast
                float4 c = acc[t];
                c.x = fmaf(g.x,w0.x,c.x); c.x = fmaf(g.y,w1.x,c.x); c.x = fmaf(g.z,w2.x,c.x); c.x = fmaf(g.w,w3.x,c.x);
                c.y = fmaf(g.x,w0.y,c.y); c.y = fmaf(g.y,w1.y,c.y); c.y = fmaf(g.z,w2.y,c.y); c.y = fmaf(g.w,w3.y,c.y);
                c.z = fmaf(g.x,w0.z,c.z); c.z = fmaf(g.y,w1.z,c.z); c.z = fmaf(g.z,w2.z,c.z); c.z = fmaf(g.w,w3.z,c.z);
                c.w = fmaf(g.x,w0.w,c.w); c.w = fmaf(g.y,w1.w,c.w); c.w = fmaf(g.z,w2.w,c.w); c.w = fmaf(g.w,w3.w,c.w);
                acc[t] = c;
            }
        }
        __builtin_amdgcn_wave_barrier();

        // epilogue per edge: LN -> ReLU -> 256x8 -> reduce -> store
        const int outbase = (is_mf ? E_FF*NET : 0) + e0*NET;
        const float4* W2v4 = (const float4*)W2;
        #pragma unroll 1
        for (int t = 0; t < 8; ++t) {
            const float4 a = acc[t];
            float s1 = (a.x+a.y)+(a.z+a.w);
            float s2 = fmaf(a.x,a.x, fmaf(a.y,a.y, fmaf(a.z,a.z, a.w*a.w)));
            #pragma unroll
            for (int m = 1; m < 64; m <<= 1) {
                s1 += __shfl_xor(s1, m, 64);
                s2 += __shfl_xor(s2, m, 64);
            }
            const float mu  = s1 * (1.f/HID2);
            const float var = s2 * (1.f/HID2) - mu*mu;
            const float rs  = rsqrtf(var + 1e-5f);
            float4 h;
            h.x = fmaxf(fmaf((a.x-mu)*rs, lg4.x, lb4.x), 0.f);
            h.y = fmaxf(fmaf((a.y-mu)*rs, lg4.y, lb4.y), 0.f);
            h.z = fmaxf(fmaf((a.z-mu)*rs, lg4.z, lb4.z), 0.f);
            h.w = fmaxf(fmaf((a.w-mu)*rs, lg4.w, lb4.w), 0.f);

            float p[8] = {0.f,0.f,0.f,0.f,0.f,0.f,0.f,0.f};
            #pragma unroll
            for (int j = 0; j < 4; ++j) {
                const float hj = (j==0)?h.x:((j==1)?h.y:((j==2)?h.z:h.w));
                const float4 lo = W2v4[(4*lane+j)*2];
                const float4 hi = W2v4[(4*lane+j)*2+1];
                p[0] = fmaf(hj, lo.x, p[0]); p[1] = fmaf(hj, lo.y, p[1]);
                p[2] = fmaf(hj, lo.z, p[2]); p[3] = fmaf(hj, lo.w, p[3]);
                p[4] = fmaf(hj, hi.x, p[4]); p[5] = fmaf(hj, hi.y, p[5]);
                p[6] = fmaf(hj, hi.z, p[6]); p[7] = fmaf(hj, hi.w, p[7]);
            }
            __builtin_amdgcn_wave_barrier();
            #pragma unroll
            for (int o = 0; o < 8; ++o) wscr[lane*9 + o] = p[o];  // [64][9] pad
            __builtin_amdgcn_wave_barrier();
            const int oo = lane & 7, ss = lane >> 3;
            float v = 0.f;
            #pragma unroll
            for (int r = 0; r < 8; ++r) v += wscr[(ss*8 + r)*9 + oo];
            v += __shfl_xor(v, 8, 64);
            v += __shfl_xor(v, 16, 64);
            v += __shfl_xor(v, 32, 64);
            if (lane < 8) out[outbase + t*NET + lane] = v + b2l;
        }
    }
}

extern "C" void kernel_launch(void* const* d_in, const int* in_sizes, int n_in,
                              void* d_out, int out_size, void* d_ws, size_t ws_size,
                              hipStream_t stream)
{
    const float* h_mol    = (const float*)d_in[0];
    const float* pos_mol  = (const float*)d_in[1];
    const float* h_frag   = (const float*)d_in[2];
    const float* pos_frag = (const float*)d_in[3];
    // d_in[4], d_in[5]: batch indices — layout is contiguous per-graph, unused
    const float* W1   = (const float*)d_in[6];
    const float* b1   = (const float*)d_in[7];
    const float* ln_g = (const float*)d_in[8];
    const float* ln_b = (const float*)d_in[9];
    const float* W2   = (const float*)d_in[10];
    const float* b2   = (const float*)d_in[11];

    float* P   = (float*)d_ws;          // 24576*256 f32 = 25.2 MB
    float* out = (float*)d_out;

    proj_kernel<<<NROWS/8, 256, 0, stream>>>(h_mol, h_frag, W1, P);

    // 74752 B dynamic LDS (>64 KiB) needs the opt-in attribute; idempotent,
    // not a stream op, safe under graph capture.
    hipFuncSetAttribute((const void*)edge_kernel,
                        hipFuncAttributeMaxDynamicSharedMemorySize, EDGE_LDS_BYTES);
    edge_kernel<<<512, 256, EDGE_LDS_BYTES, stream>>>(
        pos_mol, pos_frag, W1, b1, ln_g, ln_b, W2, b2, P, out);
}

// Round 2
// 383.881 us; speedup vs baseline: 1.2090x; 1.2090x over previous
//
#include <hip/hip_runtime.h>
#include <math.h>

// SimpleEdgePredictor on MI355X — factored formulation:
//   feat@W1 = P_a[i] + P_b[j] + smear(d)@W1s + type*w320
// R2: bf16 W1-smear in LDS (32KB) + pure-shfl epilogue transpose-reduce
//     -> 40960 B LDS/block -> 4 blocks/CU (50% occupancy vs 25%).

#define HID   128
#define MAXF  16
#define NG    64
#define NET   8
#define NB    256
#define NMOL  64
#define HID2  256

#define PMOL_ROWS (NB*NMOL)                    // 16384
#define PF_ROWS   (NB*MAXF)                    // 4096
#define NROWS     (PMOL_ROWS + 2*PF_ROWS)      // 24576
#define PFA_OFF   ((size_t)PMOL_ROWS*HID2)
#define PFB_OFF   ((size_t)(PMOL_ROWS+PF_ROWS)*HID2)

#define E_FF   (NB*MAXF*MAXF)                  // 65536
#define E_MF   (NB*NMOL*MAXF)                  // 262144
#define GRP_FF (E_FF/32)                       // 2048
#define NGROUP ((E_FF+E_MF)/32)                // 10240

#define WSCR_FLOATS 512                        // per-wave g scratch: 8 edges x 64 k
#define EDGE_LDS_BYTES (NG*HID2*2 + 4*WSCR_FLOATS*4)   // 32768 + 8192 = 40960

// ---------------- node projections: P[r] = h[r] @ W1_half ----------------
__global__ __launch_bounds__(256) void proj_kernel(
    const float* __restrict__ h_mol, const float* __restrict__ h_frag,
    const float* __restrict__ W1, float* __restrict__ P)
{
    __shared__ float hs[8][HID];               // 4 KiB
    const int tid  = threadIdx.x;
    const int row0 = blockIdx.x * 8;

    const float* src; int wrow0;
    if (row0 < PMOL_ROWS)                 { src = h_mol  + (size_t)row0*HID;                      wrow0 = 0;   }
    else if (row0 < PMOL_ROWS + PF_ROWS)  { src = h_frag + (size_t)(row0-PMOL_ROWS)*HID;          wrow0 = 0;   }
    else                                  { src = h_frag + (size_t)(row0-PMOL_ROWS-PF_ROWS)*HID;  wrow0 = HID; }

    ((float4*)&hs[0][0])[tid] = ((const float4*)src)[tid];
    __syncthreads();

    float acc[8] = {0.f,0.f,0.f,0.f,0.f,0.f,0.f,0.f};
    const float* wp = W1 + (size_t)wrow0*HID2 + tid;   // column tid, coalesced
    #pragma unroll 4
    for (int k4 = 0; k4 < HID/4; ++k4) {
        const float w0 = wp[(4*k4+0)*HID2];
        const float w1 = wp[(4*k4+1)*HID2];
        const float w2 = wp[(4*k4+2)*HID2];
        const float w3 = wp[(4*k4+3)*HID2];
        #pragma unroll
        for (int r = 0; r < 8; ++r) {
            const float4 h4 = *(const float4*)&hs[r][4*k4];
            acc[r] = fmaf(h4.x, w0, acc[r]);
            acc[r] = fmaf(h4.y, w1, acc[r]);
            acc[r] = fmaf(h4.z, w2, acc[r]);
            acc[r] = fmaf(h4.w, w3, acc[r]);
        }
    }
    float* dst = P + (size_t)row0*HID2 + tid;
    #pragma unroll
    for (int r = 0; r < 8; ++r) dst[r*HID2] = acc[r];
}

// ---------------- helpers ----------------
__device__ __forceinline__ unsigned bf16rne(float x) {
    unsigned u = __float_as_uint(x);
    return (u + 0x7fffu + ((u >> 16) & 1u)) >> 16;
}
__device__ __forceinline__ float4 bfq_to_f4(uint2 a) {
    float4 r;
    r.x = __uint_as_float(a.x << 16);
    r.y = __uint_as_float(a.x & 0xffff0000u);
    r.z = __uint_as_float(a.y << 16);
    r.w = __uint_as_float(a.y & 0xffff0000u);
    return r;
}

// ---------------- per-edge: smear-GEMM + LN + ReLU + W2 ----------------
__global__ __launch_bounds__(256,4) void edge_kernel(
    const float* __restrict__ pos_mol, const float* __restrict__ pos_frag,
    const float* __restrict__ W1, const float* __restrict__ b1,
    const float* __restrict__ ln_g, const float* __restrict__ ln_b,
    const float* __restrict__ W2, const float* __restrict__ b2,
    const float* __restrict__ P, float* __restrict__ out)
{
    extern __shared__ float smem[];
    const int tid  = threadIdx.x;
    const int lane = tid & 63;
    const int wid  = tid >> 6;
    unsigned* W1u = (unsigned*)smem;                      // [64][128] bf16-pairs = 32 KiB
    float* wscr = smem + NG*HID2/2 + wid*WSCR_FLOATS;     // per-wave g scratch

    // stage W1 rows 256..319 (smear weights) into LDS as bf16 (RNE)
    {
        const float2* s2 = (const float2*)(W1 + 256*HID2);
        #pragma unroll
        for (int i = 0; i < 32; ++i) {
            const float2 v = s2[i*256 + tid];
            W1u[i*256 + tid] = bf16rne(v.x) | (bf16rne(v.y) << 16);
        }
    }

    // per-lane constants (channels c = 4*lane .. 4*lane+3)
    const float4 b14  = ((const float4*)b1)[lane];
    const float4 lg4  = ((const float4*)ln_g)[lane];
    const float4 lb4  = ((const float4*)ln_b)[lane];
    const float4 w320 = ((const float4*)(W1 + 320*HID2))[lane];
    const float  b2l  = b2[lane & 7];
    const float  delta = 10.0f/63.0f;
    const float  off   = delta * (float)lane;
    const float  coeff = -0.5f/(delta*delta);
    __syncthreads();

    for (int grp = blockIdx.x; grp < NGROUP; grp += gridDim.x) {
        const bool is_mf = (grp >= GRP_FF);
        const int  e0 = (is_mf ? (grp - GRP_FF) : grp) * 32 + wid * 8;

        float4 acc[8];
        #pragma unroll
        for (int t = 0; t < 8; ++t) {
            const int e = e0 + t;
            int arow, brow;
            const float* pa;
            if (is_mf) {
                const int bg = e >> 10, m = (e >> 4) & 63, j = e & 15;
                arow = bg*NMOL + m; brow = bg*MAXF + j;
                pa = pos_mol + (size_t)arow*3;
            } else {
                const int bg = e >> 8, i = (e >> 4) & 15, j = e & 15;
                arow = bg*MAXF + i; brow = bg*MAXF + j;
                pa = pos_frag + (size_t)arow*3;
            }
            const float* pb = pos_frag + (size_t)brow*3;
            const float dx = pa[0]-pb[0], dy = pa[1]-pb[1], dz = pa[2]-pb[2];
            const float d  = sqrtf(fmaf(dx,dx, fmaf(dy,dy, fmaf(dz,dz, 1e-12f))));
            const float dd = d - off;
            wscr[t*64 + lane] = expf(coeff*dd*dd);    // g[t][k=lane]

            const float* pra = P + (is_mf ? (size_t)arow*HID2 : PFA_OFF + (size_t)arow*HID2);
            const float* prb = P + PFB_OFF + (size_t)brow*HID2;
            const float4 av = ((const float4*)pra)[lane];
            const float4 bv = ((const float4*)prb)[lane];
            float4 c;
            c.x = av.x + bv.x + b14.x;
            c.y = av.y + bv.y + b14.y;
            c.z = av.z + bv.z + b14.z;
            c.w = av.w + bv.w + b14.w;
            if (is_mf) { c.x += w320.x; c.y += w320.y; c.z += w320.z; c.w += w320.w; }
            acc[t] = c;
        }
        __builtin_amdgcn_wave_barrier();   // wave-synchronous LDS g handoff

        // smear GEMM: acc[t][c] += sum_k g[t][k] * W1s[k][c]   (W1s bf16 in LDS)
        const uint2* wv = (const uint2*)W1u;     // [64 rows][64 lane-slices]
        #pragma unroll 2
        for (int k4 = 0; k4 < 16; ++k4) {
            const float4 w0 = bfq_to_f4(wv[(4*k4+0)*64 + lane]);
            const float4 w1 = bfq_to_f4(wv[(4*k4+1)*64 + lane]);
            const float4 w2 = bfq_to_f4(wv[(4*k4+2)*64 + lane]);
            const float4 w3 = bfq_to_f4(wv[(4*k4+3)*64 + lane]);
            #pragma unroll
            for (int t = 0; t < 8; ++t) {
                const float4 g = *(const float4*)&wscr[t*64 + 4*k4]; // broadcast
                float4 c = acc[t];
                c.x = fmaf(g.x,w0.x,c.x); c.x = fmaf(g.y,w1.x,c.x); c.x = fmaf(g.z,w2.x,c.x); c.x = fmaf(g.w,w3.x,c.x);
                c.y = fmaf(g.x,w0.y,c.y); c.y = fmaf(g.y,w1.y,c.y); c.y = fmaf(g.z,w2.y,c.y); c.y = fmaf(g.w,w3.y,c.y);
                c.z = fmaf(g.x,w0.z,c.z); c.z = fmaf(g.y,w1.z,c.z); c.z = fmaf(g.z,w2.z,c.z); c.z = fmaf(g.w,w3.z,c.z);
                c.w = fmaf(g.x,w0.w,c.w); c.w = fmaf(g.y,w1.w,c.w); c.w = fmaf(g.z,w2.w,c.w); c.w = fmaf(g.w,w3.w,c.w);
                acc[t] = c;
            }
        }
        __builtin_amdgcn_wave_barrier();

        // epilogue: per edge LN -> ReLU -> 256x8 W2; cross-lane via shfl only
        const float4* W2v4 = (const float4*)W2;
        float vpart[8];                         // per-t partial (o = lane&7, over 8-lane subgroup)
        #pragma unroll 1
        for (int t = 0; t < 8; ++t) {
            const float4 a = acc[t];
            float s1 = (a.x+a.y)+(a.z+a.w);
            float s2 = fmaf(a.x,a.x, fmaf(a.y,a.y, fmaf(a.z,a.z, a.w*a.w)));
            #pragma unroll
            for (int m = 1; m < 64; m <<= 1) {
                s1 += __shfl_xor(s1, m, 64);
                s2 += __shfl_xor(s2, m, 64);
            }
            const float mu  = s1 * (1.f/HID2);
            const float var = s2 * (1.f/HID2) - mu*mu;
            const float rs  = rsqrtf(var + 1e-5f);
            float4 h;
            h.x = fmaxf(fmaf((a.x-mu)*rs, lg4.x, lb4.x), 0.f);
            h.y = fmaxf(fmaf((a.y-mu)*rs, lg4.y, lb4.y), 0.f);
            h.z = fmaxf(fmaf((a.z-mu)*rs, lg4.z, lb4.z), 0.f);
            h.w = fmaxf(fmaf((a.w-mu)*rs, lg4.w, lb4.w), 0.f);

            float p[8] = {0.f,0.f,0.f,0.f,0.f,0.f,0.f,0.f};
            #pragma unroll
            for (int j = 0; j < 4; ++j) {
                const float hj = (j==0)?h.x:((j==1)?h.y:((j==2)?h.z:h.w));
                const float4 lo = W2v4[(4*lane+j)*2];
                const float4 hi = W2v4[(4*lane+j)*2+1];
                p[0] = fmaf(hj, lo.x, p[0]); p[1] = fmaf(hj, lo.y, p[1]);
                p[2] = fmaf(hj, lo.z, p[2]); p[3] = fmaf(hj, lo.w, p[3]);
                p[4] = fmaf(hj, hi.x, p[4]); p[5] = fmaf(hj, hi.y, p[5]);
                p[6] = fmaf(hj, hi.z, p[6]); p[7] = fmaf(hj, hi.w, p[7]);
            }
            // shfl transpose-reduce over o-bits (lane bits 0..2)
            float q4[4];
            {
                const int b = lane & 1;
                #pragma unroll
                for (int i2 = 0; i2 < 4; ++i2) {
                    const float send = b ? p[2*i2] : p[2*i2+1];
                    q4[i2] = (b ? p[2*i2+1] : p[2*i2]) + __shfl_xor(send, 1, 64);
                }
            }
            float q2[2];
            {
                const int b = lane & 2;
                #pragma unroll
                for (int i2 = 0; i2 < 2; ++i2) {
                    const float send = b ? q4[2*i2] : q4[2*i2+1];
                    q2[i2] = (b ? q4[2*i2+1] : q4[2*i2]) + __shfl_xor(send, 2, 64);
                }
            }
            {
                const int b = lane & 4;
                const float send = b ? q2[0] : q2[1];
                vpart[t] = (b ? q2[1] : q2[0]) + __shfl_xor(send, 4, 64);
            }
        }
        // transpose-reduce over subgroup bits (lane bits 3..5), indexed by t
        float u4[4];
        {
            const int b = lane & 8;
            #pragma unroll
            for (int i2 = 0; i2 < 4; ++i2) {
                const float send = b ? vpart[2*i2] : vpart[2*i2+1];
                u4[i2] = (b ? vpart[2*i2+1] : vpart[2*i2]) + __shfl_xor(send, 8, 64);
            }
        }
        float u2[2];
        {
            const int b = lane & 16;
            #pragma unroll
            for (int i2 = 0; i2 < 2; ++i2) {
                const float send = b ? u4[2*i2] : u4[2*i2+1];
                u2[i2] = (b ? u4[2*i2+1] : u4[2*i2]) + __shfl_xor(send, 16, 64);
            }
        }
        float uf;
        {
            const int b = lane & 32;
            const float send = b ? u2[0] : u2[1];
            uf = (b ? u2[1] : u2[0]) + __shfl_xor(send, 32, 64);
        }
        // lane l holds out for edge e0 + (l>>3), channel l&7 -> coalesced 256B store
        const int wavebase = (is_mf ? E_FF*NET : 0) + e0*NET;
        out[wavebase + lane] = uf + b2l;
    }
}

extern "C" void kernel_launch(void* const* d_in, const int* in_sizes, int n_in,
                              void* d_out, int out_size, void* d_ws, size_t ws_size,
                              hipStream_t stream)
{
    const float* h_mol    = (const float*)d_in[0];
    const float* pos_mol  = (const float*)d_in[1];
    const float* h_frag   = (const float*)d_in[2];
    const float* pos_frag = (const float*)d_in[3];
    // d_in[4], d_in[5]: batch indices — layout is contiguous per-graph, unused
    const float* W1   = (const float*)d_in[6];
    const float* b1   = (const float*)d_in[7];
    const float* ln_g = (const float*)d_in[8];
    const float* ln_b = (const float*)d_in[9];
    const float* W2   = (const float*)d_in[10];
    const float* b2   = (const float*)d_in[11];

    float* P   = (float*)d_ws;          // 24576*256 f32 = 25.2 MB
    float* out = (float*)d_out;

    proj_kernel<<<NROWS/8, 256, 0, stream>>>(h_mol, h_frag, W1, P);
    edge_kernel<<<1024, 256, EDGE_LDS_BYTES, stream>>>(
        pos_mol, pos_frag, W1, b1, ln_g, ln_b, W2, b2, P, out);
}

// Round 4
// 236.206 us; speedup vs baseline: 1.9648x; 1.6252x over previous
//
#include <hip/hip_runtime.h>
#include <hip/hip_bf16.h>
#include <math.h>

// SimpleEdgePredictor on MI355X — R4: MFMA formulation (R3 + staging fix).
//   h^T = W1sT @ gT  (16x16x32 bf16 MFMA, C-init = P_a + P_b')
//   LN/ReLU in C-layout (4-lane stats via shfl_xor 16/32)
//   out^T = W2T @ hT (MFMA, W2T A-frags register-resident)
// R4 fixes: W1T staging word offset 2*k3 (was 4*k3 — wrote wrong words and
// spilled across rows); wave_barrier around per-wave hbuf handoff.

#define HID   128
#define HID2  256
#define NG    64
#define NET   8
#define NB    256
#define NMOL  64
#define MAXF  16

// P row layout (rows of 256 f32):
//   [0,16384)      mol  = h_mol  @ W1[0:128]
//   [16384,20480)  fa   = h_frag @ W1[0:128]
//   [20480,24576)  bff  = h_frag @ W1[128:256] + b1
//   [24576,28672)  bmf  = bff + w320
#define PMOL   16384
#define R_FA   16384
#define R_BFF  20480
#define R_BMF  24576
#define PROJ_ROWS 24576

#define E_FF     65536
#define TILES_FF 4096
#define NTILES   20480      // 16-edge tiles total
#define EDGE_GRID 1280      // 16 tiles/block = 4 iters x 4 waves

#define EDGE_LDS_WORDS (8192 + 512 + 4*2048)   // W1T + params + 4 h-bufs
#define EDGE_LDS_BYTES (EDGE_LDS_WORDS*4)      // 67584

typedef float f32x4 __attribute__((ext_vector_type(4)));
typedef short bf16x8 __attribute__((ext_vector_type(8)));
union U4 { uint4 u; bf16x8 b; };

__device__ __forceinline__ unsigned pk_bf16(float lo, float hi) {
    __hip_bfloat162 h = __float22bfloat162_rn(float2{lo, hi});
    union { __hip_bfloat162 h; unsigned u; } c; c.h = h;
    return c.u;
}

// ---------------- node projections (f32 VALU, 16 rows/block) ----------------
__global__ __launch_bounds__(256) void proj_kernel(
    const float* __restrict__ h_mol, const float* __restrict__ h_frag,
    const float* __restrict__ W1, const float* __restrict__ b1,
    float* __restrict__ P)
{
    __shared__ float hs[16*HID];               // 8 KiB
    const int tid  = threadIdx.x;
    const int row0 = blockIdx.x * 16;

    const float* src; int wrow0, mode;
    if (row0 < PMOL)        { src = h_mol  + (size_t)row0*HID;          wrow0 = 0;   mode = 0; }
    else if (row0 < R_BFF)  { src = h_frag + (size_t)(row0-R_FA)*HID;   wrow0 = 0;   mode = 0; }
    else                    { src = h_frag + (size_t)(row0-R_BFF)*HID;  wrow0 = HID; mode = 1; }

    ((float4*)hs)[tid]       = ((const float4*)src)[tid];
    ((float4*)hs)[tid + 256] = ((const float4*)src)[tid + 256];
    __syncthreads();

    float acc[16];
    #pragma unroll
    for (int r = 0; r < 16; ++r) acc[r] = 0.f;

    const float* wp = W1 + (size_t)wrow0*HID2 + tid;   // column tid, coalesced
    #pragma unroll 4
    for (int k4 = 0; k4 < HID/4; ++k4) {
        const float w0 = wp[(4*k4+0)*HID2];
        const float w1 = wp[(4*k4+1)*HID2];
        const float w2 = wp[(4*k4+2)*HID2];
        const float w3 = wp[(4*k4+3)*HID2];
        #pragma unroll
        for (int r = 0; r < 16; ++r) {
            const float4 h4 = *(const float4*)&hs[r*HID + 4*k4];  // broadcast
            acc[r] = fmaf(h4.x, w0, fmaf(h4.y, w1, fmaf(h4.z, w2, fmaf(h4.w, w3, acc[r]))));
        }
    }
    if (mode == 0) {
        float* d = P + (size_t)row0*HID2 + tid;
        #pragma unroll
        for (int r = 0; r < 16; ++r) d[r*HID2] = acc[r];
    } else {
        const float bb = b1[tid];
        const float ww = W1[(size_t)320*HID2 + tid];
        float* d1 = P + (size_t)row0*HID2 + tid;             // bff (row0 in [20480,24576))
        float* d2 = d1 + (size_t)4096*HID2;                  // bmf
        #pragma unroll
        for (int r = 0; r < 16; ++r) {
            const float v = acc[r] + bb;
            d1[r*HID2] = v;
            d2[r*HID2] = v + ww;
        }
    }
}

// ---------------- per-edge MFMA kernel ----------------
__global__ __launch_bounds__(256,2) void edge_kernel(
    const float* __restrict__ pos_mol, const float* __restrict__ pos_frag,
    const float* __restrict__ W1, const float* __restrict__ ln_g,
    const float* __restrict__ ln_b, const float* __restrict__ W2,
    const float* __restrict__ b2, const float* __restrict__ P,
    float* __restrict__ out)
{
    extern __shared__ unsigned sm[];
    unsigned* W1T = sm;                  // [256 ch][32 u32(bf16x2)], XOR-swizzled
    float*    pp  = (float*)(sm + 8192); // [256 ch][2] = (ln_g, ln_b)
    const int tid = threadIdx.x, lane = tid & 63, wid = tid >> 6;
    const int c15 = lane & 15, q = lane >> 4;
    const unsigned sz = (unsigned)(c15 & 7) << 2;    // word-index XOR (bank swizzle)
    unsigned* hbuf = sm + 8704 + wid*2048;           // per-wave [16 edge][128 u32]

    // ---- stage W1 rows 256..319 transposed to bf16 [ch][k], swizzled ----
    {
        const float* colp = W1 + (size_t)256*HID2 + tid;    // column tid
        #pragma unroll 4
        for (int k3 = 0; k3 < 16; ++k3) {
            const float a0 = colp[(4*k3+0)*HID2];
            const float a1 = colp[(4*k3+1)*HID2];
            const float a2 = colp[(4*k3+2)*HID2];
            const float a3 = colp[(4*k3+3)*HID2];
            // 4 bf16 = 2 words per chunk -> word offset 2*k3 within 32-word row
            const unsigned w = ((unsigned)(tid*32 + 2*k3)) ^ (((unsigned)(tid & 7)) << 2);
            *(uint2*)&W1T[w] = make_uint2(pk_bf16(a0, a1), pk_bf16(a2, a3));
        }
        pp[2*tid]   = ln_g[tid];
        pp[2*tid+1] = ln_b[tid];
    }

    // ---- W2^T A-fragments, register-resident (rows o>=8 zero) ----
    unsigned a2f[8][4];
    {
        const int o = c15;
        #pragma unroll
        for (int ks = 0; ks < 8; ++ks)
            #pragma unroll
            for (int j = 0; j < 4; ++j) {
                float lo = 0.f, hi = 0.f;
                if (o < 8) {
                    lo = W2[(size_t)(32*ks + 8*q + 2*j    )*NET + o];
                    hi = W2[(size_t)(32*ks + 8*q + 2*j + 1)*NET + o];
                }
                a2f[ks][j] = pk_bf16(lo, hi);
            }
    }
    float4 b2v = make_float4(0.f,0.f,0.f,0.f);
    if (q < 2) b2v = ((const float4*)b2)[q];

    // ---- gaussian slot tables (lane-const): k = 32*ks + 8*q + i ----
    const float delta = 10.0f/63.0f;
    const float coeff = -0.5f/(delta*delta);
    const float cl2e  = coeff * 1.44269504088896340736f;   // fold log2(e)
    float c1t[16], c2t[16];
    #pragma unroll
    for (int s = 0; s < 16; ++s) {
        const int k = 32*(s>>3) + 8*q + (s&7);
        const float off = delta * (float)k;
        c1t[s] = off;
        c2t[s] = cl2e*off*off;
    }
    __syncthreads();

    #pragma unroll 1
    for (int it = 0; it < 4; ++it) {
        const int tile = blockIdx.x*16 + it*4 + wid;
        const bool isff = (tile < TILES_FF);
        int arow, browbase;
        const float* pa; const float* Pa; const float* Pb;
        size_t obase;
        if (isff) {
            const int bg = tile >> 4, i = tile & 15;
            arow = bg*MAXF + i; browbase = bg*MAXF;
            pa = pos_frag + (size_t)arow*3;
            Pa = P + (size_t)(R_FA + arow)*HID2;
            Pb = P + (size_t)(R_BFF + browbase)*HID2;
            obase = (size_t)(tile << 4) * NET;
        } else {
            const int tt = tile - TILES_FF, bg = tt >> 6, m = tt & 63;
            arow = bg*NMOL + m; browbase = bg*MAXF;
            pa = pos_mol + (size_t)arow*3;
            Pa = P + (size_t)arow*HID2;
            Pb = P + (size_t)(R_BMF + browbase)*HID2;
            obase = (size_t)(E_FF + (tt << 4)) * NET;
        }

        // distance for this lane's edge (col = c15); wave-uniform a-side
        const float* pb = pos_frag + (size_t)(browbase + c15)*3;
        const float dx = pa[0]-pb[0], dy = pa[1]-pb[1], dz = pa[2]-pb[2];
        const float d  = sqrtf(fmaf(dx,dx, fmaf(dy,dy, fmaf(dz,dz, 1e-12f))));
        const float Ad = cl2e*d*d;
        const float Bd = -2.f*cl2e*d;

        // g B-fragments in-register (exp2 with folded constants)
        U4 gB0, gB1;
        {
            unsigned g0[4], g1[4];
            #pragma unroll
            for (int j = 0; j < 4; ++j) {
                const float e0 = exp2f(fmaf(Bd, c1t[2*j  ], c2t[2*j  ]) + Ad);
                const float e1 = exp2f(fmaf(Bd, c1t[2*j+1], c2t[2*j+1]) + Ad);
                g0[j] = pk_bf16(e0, e1);
                const float e2 = exp2f(fmaf(Bd, c1t[8+2*j  ], c2t[8+2*j  ]) + Ad);
                const float e3 = exp2f(fmaf(Bd, c1t[8+2*j+1], c2t[8+2*j+1]) + Ad);
                g1[j] = pk_bf16(e2, e3);
            }
            gB0.u = make_uint4(g0[0], g0[1], g0[2], g0[3]);
            gB1.u = make_uint4(g1[0], g1[1], g1[2], g1[3]);
        }

        // GEMM1: acc[nt] = P_a + P_b' + W1sT-tile @ g
        f32x4 acc[16];
        const float* PaQ = Pa + 4*q;
        const float* PbQ = Pb + (size_t)c15*HID2 + 4*q;
        #pragma unroll
        for (int nt = 0; nt < 16; ++nt) {
            const unsigned chw = (unsigned)((16*nt + c15)*32 + 4*q);
            U4 a1a, a1b;
            a1a.u = *(const uint4*)&W1T[(chw     ) ^ sz];
            a1b.u = *(const uint4*)&W1T[(chw + 16) ^ sz];
            const float4 pa4 = *(const float4*)(PaQ + 16*nt);
            const float4 pb4 = *(const float4*)(PbQ + 16*nt);
            f32x4 c;
            c.x = pa4.x + pb4.x; c.y = pa4.y + pb4.y;
            c.z = pa4.z + pb4.z; c.w = pa4.w + pb4.w;
            c = __builtin_amdgcn_mfma_f32_16x16x32_bf16(a1a.b, gB0.b, c, 0, 0, 0);
            c = __builtin_amdgcn_mfma_f32_16x16x32_bf16(a1b.b, gB1.b, c, 0, 0, 0);
            acc[nt] = c;
        }

        // LayerNorm stats: lane holds 64 of 256 channels; reduce over 4 lanes
        float s1 = 0.f, s2 = 0.f;
        #pragma unroll
        for (int nt = 0; nt < 16; ++nt) {
            const f32x4 c = acc[nt];
            s1 += (c.x + c.y) + (c.z + c.w);
            s2  = fmaf(c.x,c.x, fmaf(c.y,c.y, fmaf(c.z,c.z, fmaf(c.w,c.w, s2))));
        }
        s1 += __shfl_xor(s1, 16, 64); s1 += __shfl_xor(s1, 32, 64);
        s2 += __shfl_xor(s2, 16, 64); s2 += __shfl_xor(s2, 32, 64);
        const float mu  = s1 * (1.f/HID2);
        const float var = fmaf(-mu, mu, s2 * (1.f/HID2));
        const float rs  = rsqrtf(var + 1e-5f);
        const float c0  = -mu * rs;

        // next-iter hbuf writes must not pass this iter's reads (WAR) and
        // GEMM2 reads must not pass these writes (RAW): pin issue order.
        __builtin_amdgcn_wave_barrier();

        // LN + ReLU + pack bf16 + stage h^T tile (swizzled, per-wave)
        #pragma unroll
        for (int nt = 0; nt < 16; ++nt) {
            const float* pq = pp + (16*nt + 4*q)*2;
            const float4 g01 = *(const float4*)pq;        // lg0 lb0 lg1 lb1
            const float4 g23 = *(const float4*)(pq + 4);  // lg2 lb2 lg3 lb3
            const f32x4 c = acc[nt];
            const float h0 = fmaxf(fmaf(fmaf(c.x, rs, c0), g01.x, g01.y), 0.f);
            const float h1 = fmaxf(fmaf(fmaf(c.y, rs, c0), g01.z, g01.w), 0.f);
            const float h2 = fmaxf(fmaf(fmaf(c.z, rs, c0), g23.x, g23.y), 0.f);
            const float h3 = fmaxf(fmaf(fmaf(c.w, rs, c0), g23.z, g23.w), 0.f);
            const unsigned w = ((unsigned)(c15*128 + 8*nt + 2*q)) ^ sz;
            *(uint2*)&hbuf[w] = make_uint2(pk_bf16(h0, h1), pk_bf16(h2, h3));
        }
        __builtin_amdgcn_wave_barrier();

        // GEMM2: out^T = W2T @ hT  (K=256, 8 k-steps)
        f32x4 o2 = {0.f, 0.f, 0.f, 0.f};
        #pragma unroll
        for (int ks = 0; ks < 8; ++ks) {
            U4 a2u, b2u;
            a2u.u = make_uint4(a2f[ks][0], a2f[ks][1], a2f[ks][2], a2f[ks][3]);
            b2u.u = *(const uint4*)&hbuf[((unsigned)(c15*128 + 16*ks + 4*q)) ^ sz];
            o2 = __builtin_amdgcn_mfma_f32_16x16x32_bf16(a2u.b, b2u.b, o2, 0, 0, 0);
        }
        __builtin_amdgcn_wave_barrier();

        // D rows 0..7 are the 8 outputs; lane (q<2, c15) stores edge c15, o=4q+r
        if (lane < 32) {
            const float4 r = make_float4(o2.x + b2v.x, o2.y + b2v.y,
                                         o2.z + b2v.z, o2.w + b2v.w);
            *(float4*)(out + obase + (size_t)c15*NET + 4*q) = r;
        }
    }
}

extern "C" void kernel_launch(void* const* d_in, const int* in_sizes, int n_in,
                              void* d_out, int out_size, void* d_ws, size_t ws_size,
                              hipStream_t stream)
{
    const float* h_mol    = (const float*)d_in[0];
    const float* pos_mol  = (const float*)d_in[1];
    const float* h_frag   = (const float*)d_in[2];
    const float* pos_frag = (const float*)d_in[3];
    // d_in[4], d_in[5]: batch indices — contiguous per-graph layout, unused
    const float* W1   = (const float*)d_in[6];
    const float* b1   = (const float*)d_in[7];
    const float* ln_g = (const float*)d_in[8];
    const float* ln_b = (const float*)d_in[9];
    const float* W2   = (const float*)d_in[10];
    const float* b2   = (const float*)d_in[11];

    float* P   = (float*)d_ws;        // 28672 * 256 f32 = 29.36 MB
    float* outp = (float*)d_out;

    proj_kernel<<<PROJ_ROWS/16, 256, 0, stream>>>(h_mol, h_frag, W1, b1, P);

    hipFuncSetAttribute((const void*)edge_kernel,
                        hipFuncAttributeMaxDynamicSharedMemorySize, EDGE_LDS_BYTES);
    edge_kernel<<<EDGE_GRID, 256, EDGE_LDS_BYTES, stream>>>(
        pos_mol, pos_frag, W1, ln_g, ln_b, W2, b2, P, outp);
}